// Round 3
// baseline (74.896 us; speedup 1.0000x reference)
//
#include <hip/hip_runtime.h>
#include <math.h>

// QuanvolutionHybrid, collapsed form, v3.
//   z0 = r^T G r   (G = real form of U' Z0 U with embedding i-phases folded in)
//   q  = cos(z0)*zH - sin(z0)*yH
// v3 change: the 16-gate simulation of U is split into two independent 8-gate
// halves run in PARALLEL (lanes 0-15: H1 columns, lanes 16-31: H2 columns),
// combined with a 256-thread 16x16 complex matvec U = H2*H1. Cuts the longest
// serial phase of the per-block precompute roughly in half.

struct c32 { float re, im; };

__device__ __forceinline__ c32 cmul(c32 a, c32 b) {
    return { fmaf(a.re, b.re, -a.im * b.im), fmaf(a.re, b.im, a.im * b.re) };
}
__device__ __forceinline__ c32 cmulc(c32 a, c32 b) {  // conj(a)*b
    return { fmaf(a.re, b.re, a.im * b.im), fmaf(a.re, b.im, -a.im * b.re) };
}
__device__ __forceinline__ c32 cadd(c32 a, c32 b) { return { a.re + b.re, a.im + b.im }; }
__device__ __forceinline__ c32 csub(c32 a, c32 b) { return { a.re - b.re, a.im - b.im }; }

template<int W>
__device__ __forceinline__ void apply1(c32 amp[16], c32 u00, c32 u01, c32 u10, c32 u11) {
    constexpr int s = 8 >> W;
    #pragma unroll
    for (int i = 0; i < 16; ++i) {
        if (i & s) continue;  // constant-folded after unroll
        c32 a = amp[i], b = amp[i + s];
        amp[i]     = cadd(cmul(u00, a), cmul(u01, b));
        amp[i + s] = cadd(cmul(u10, a), cmul(u11, b));
    }
}

template<int C, int T>
__device__ __forceinline__ void cnot4(c32 amp[16]) {
    constexpr int sc = 8 >> C, st = 8 >> T;
    #pragma unroll
    for (int i = 0; i < 16; ++i) {
        if ((i & sc) && !(i & st)) {
            c32 tmp = amp[i]; amp[i] = amp[i | st]; amp[i | st] = tmp;
        }
    }
}

// PennyLane Rot(phi, theta, omega) = RZ(omega) RY(theta) RZ(phi)
__device__ __forceinline__ void make_rot(float phi, float th, float om,
                                         c32& u00, c32& u01, c32& u10, c32& u11) {
    float sh, ch; sincosf(th * 0.5f, &sh, &ch);
    float spo, cpo; sincosf((phi + om) * 0.5f, &spo, &cpo);
    float spm, cpm; sincosf((phi - om) * 0.5f, &spm, &cpm);
    u00 = {  cpo * ch, -spo * ch };
    u01 = { -cpm * sh, -spm * sh };
    u10 = {  cpm * sh, -spm * sh };
    u11 = {  cpo * ch,  spo * ch };
}

// Simulate one SEL "app" (2 layers: range 1 then range 2), gates [base, base+8)
__device__ __forceinline__ void sim_app(c32 amp[16], const c32 (*gm)[4], int base) {
    apply1<0>(amp, gm[base+0][0], gm[base+0][1], gm[base+0][2], gm[base+0][3]);
    apply1<1>(amp, gm[base+1][0], gm[base+1][1], gm[base+1][2], gm[base+1][3]);
    apply1<2>(amp, gm[base+2][0], gm[base+2][1], gm[base+2][2], gm[base+2][3]);
    apply1<3>(amp, gm[base+3][0], gm[base+3][1], gm[base+3][2], gm[base+3][3]);
    cnot4<0,1>(amp); cnot4<1,2>(amp); cnot4<2,3>(amp); cnot4<3,0>(amp);  // r = 1
    apply1<0>(amp, gm[base+4][0], gm[base+4][1], gm[base+4][2], gm[base+4][3]);
    apply1<1>(amp, gm[base+5][0], gm[base+5][1], gm[base+5][2], gm[base+5][3]);
    apply1<2>(amp, gm[base+6][0], gm[base+6][1], gm[base+6][2], gm[base+6][3]);
    apply1<3>(amp, gm[base+7][0], gm[base+7][1], gm[base+7][2], gm[base+7][3]);
    cnot4<0,2>(amp); cnot4<1,3>(amp); cnot4<2,0>(amp); cnot4<3,1>(amp);  // r = 2
}

#define GP 20  // padded row stride of Gq in floats (breaks bank conflicts)

__global__ __launch_bounds__(256)
void quanv_hybrid_kernel(const float* __restrict__ x,
                         const float* __restrict__ wq,    // [2,2,4,3] = 16 gates x 3
                         const float* __restrict__ wfc,   // [3,3,1,3] =  9 gates x 3
                         const float* __restrict__ Wout,  // [10,1]
                         const float* __restrict__ bout,  // [10]
                         float* __restrict__ out,         // [B,10]
                         int B)
{
    const int tid = threadIdx.x;
    const int j   = tid & 15;          // lane's j-slice / output index
    const int img = blockIdx.x * 16 + (tid >> 4);
    const int imgc = (img < B) ? img : (B - 1);

    __shared__ c32   gmat[25][4];                 // 16 quanv Rot + 9 qfc Rot
    __shared__ float Ar[16][16], Ai[16][16];      // H1 columns
    __shared__ float Br_[16][16], Bi_[16][16];    // H2 columns
    __shared__ float Ur[16][16], Ui[16][16];      // U = H2*H1
    __shared__ float Gqs[16 * GP];
    __shared__ float yz[2];                       // {yH, zH}

    // ---- Hoisted global loads: latency overlaps the precompute ----
    const float* xb = x + (size_t)imgc * 784;
    float2 a01 = *reinterpret_cast<const float2*>(xb);        // img[0,0..1]
    float2 a23 = *reinterpret_cast<const float2*>(xb + 28);   // img[1,0..1]
    float Wj = (j < 10) ? Wout[j] : 0.f;
    float bj = (j < 10) ? bout[j] : 0.f;

    // ---- Phase 0: 25 Rot matrices, one per thread ----
    if (tid < 25) {
        const float* p = (tid < 16) ? (wq + 3 * tid) : (wfc + 3 * (tid - 16));
        c32 a, bb, c, d;
        make_rot(p[0], p[1], p[2], a, bb, c, d);
        gmat[tid][0] = a; gmat[tid][1] = bb; gmat[tid][2] = c; gmat[tid][3] = d;
    }
    __syncthreads();

    // ---- Phase 1a: two 8-gate halves in parallel; V on lane 32 ----
    if (tid < 32) {
        const int t = tid & 15;
        c32 amp[16];
        #pragma unroll
        for (int i = 0; i < 16; ++i) amp[i] = { 0.f, 0.f };
        amp[t].re = 1.f;
        if (tid < 16) {
            sim_app(amp, gmat, 0);                // app 0 (gates 0-7)
            #pragma unroll
            for (int i = 0; i < 16; ++i) { Ar[i][t] = amp[i].re; Ai[i][t] = amp[i].im; }
        } else {
            sim_app(amp, gmat, 8);                // app 1 (gates 8-15)
            #pragma unroll
            for (int i = 0; i < 16; ++i) { Br_[i][t] = amp[i].re; Bi_[i][t] = amp[i].im; }
        }
    } else if (tid == 32) {
        // V = U9 ... U1 of the qfc chain
        c32 v00 = {1.f, 0.f}, v01 = {0.f, 0.f}, v10 = {0.f, 0.f}, v11 = {1.f, 0.f};
        #pragma unroll
        for (int g = 0; g < 9; ++g) {
            c32 u00 = gmat[16+g][0], u01 = gmat[16+g][1], u10 = gmat[16+g][2], u11 = gmat[16+g][3];
            c32 n00 = cadd(cmul(u00, v00), cmul(u01, v10));
            c32 n01 = cadd(cmul(u00, v01), cmul(u01, v11));
            c32 n10 = cadd(cmul(u10, v00), cmul(u11, v10));
            c32 n11 = cadd(cmul(u10, v01), cmul(u11, v11));
            v00 = n00; v01 = n01; v10 = n10; v11 = n11;
        }
        float zH = fmaf(v00.re, v00.re, v00.im * v00.im)
                 - fmaf(v10.re, v10.re, v10.im * v10.im);
        c32 h01 = csub(cmulc(v00, v01), cmulc(v10, v11));
        yz[0] = -h01.im; yz[1] = zH;
    }
    __syncthreads();

    // ---- Phase 1b: U[i][t] = sum_k H2[i][k] * H1[k][t], one entry/thread ----
    {
        const int i = tid >> 4, t = tid & 15;
        c32 acc = { 0.f, 0.f };
        #pragma unroll
        for (int k = 0; k < 16; ++k) {
            c32 bk = { Br_[i][k], Bi_[i][k] };   // broadcast across t-lanes
            c32 ak = { Ar[k][t],  Ai[k][t]  };
            acc = cadd(acc, cmul(bk, ak));
        }
        Ur[i][t] = acc.re; Ui[i][t] = acc.im;
    }
    __syncthreads();

    // ---- Phase 2: one Gq entry per thread ----
    {
        const int jj = tid >> 4, kk = tid & 15;
        float mre = 0.f, mim = 0.f;
        #pragma unroll
        for (int i = 0; i < 16; ++i) {
            float ar = Ur[i][jj], ai = Ui[i][jj], br = Ur[i][kk], bi = Ui[i][kk];
            float re = fmaf(ar, br,  ai * bi);
            float im = fmaf(ar, bi, -ai * br);
            if (i < 8) { mre += re; mim += im; } else { mre -= re; mim -= im; }
        }
        int m4 = (__popc(jj) - __popc(kk)) & 3;
        float g = (m4 == 0) ? mre : (m4 == 1) ? -mim : (m4 == 2) ? -mre : mim;
        Gqs[jj * GP + kk] = g;
    }
    __syncthreads();

    // ---- Phase 3: per-image, 16 lanes cooperate ----
    float s0, c0, s1, c1, s2, c2, s3, c3;
    sincosf(a01.x * 0.5f, &s0, &c0);
    sincosf(a01.y * 0.5f, &s1, &c1);
    sincosf(a23.x * 0.5f, &s2, &c2);
    sincosf(a23.y * 0.5f, &s3, &c3);

    float A4[4] = { c0 * c1, c0 * s1, s0 * c1, s0 * s1 };   // wires 0,1
    float Bv[4] = { c2 * c3, c2 * s3, s2 * c3, s2 * s3 };   // wires 2,3
    float r[16];
    #pragma unroll
    for (int k = 0; k < 16; ++k) r[k] = A4[k >> 2] * Bv[k & 3];

    const float* gr = &Gqs[j * GP];
    float4 g0 = *reinterpret_cast<const float4*>(gr + 0);
    float4 g1 = *reinterpret_cast<const float4*>(gr + 4);
    float4 g2 = *reinterpret_cast<const float4*>(gr + 8);
    float4 g3 = *reinterpret_cast<const float4*>(gr + 12);
    float t = 0.f;
    t = fmaf(g0.x, r[0],  t); t = fmaf(g0.y, r[1],  t);
    t = fmaf(g0.z, r[2],  t); t = fmaf(g0.w, r[3],  t);
    t = fmaf(g1.x, r[4],  t); t = fmaf(g1.y, r[5],  t);
    t = fmaf(g1.z, r[6],  t); t = fmaf(g1.w, r[7],  t);
    t = fmaf(g2.x, r[8],  t); t = fmaf(g2.y, r[9],  t);
    t = fmaf(g2.z, r[10], t); t = fmaf(g2.w, r[11], t);
    t = fmaf(g3.x, r[12], t); t = fmaf(g3.y, r[13], t);
    t = fmaf(g3.z, r[14], t); t = fmaf(g3.w, r[15], t);

    float z0 = r[j] * t;
    z0 += __shfl_xor(z0, 1);
    z0 += __shfl_xor(z0, 2);
    z0 += __shfl_xor(z0, 4);
    z0 += __shfl_xor(z0, 8);   // all 16 lanes of the group hold z0

    float sz, cz; sincosf(z0, &sz, &cz);
    float q = fmaf(cz, yz[1], -sz * yz[0]);

    // Linear(1,10) + log_softmax, lane-parallel over j
    float lg = (j < 10) ? fmaf(q, Wj, bj) : -1e30f;
    float m = lg;
    m = fmaxf(m, __shfl_xor(m, 1));
    m = fmaxf(m, __shfl_xor(m, 2));
    m = fmaxf(m, __shfl_xor(m, 4));
    m = fmaxf(m, __shfl_xor(m, 8));

    float e = (j < 10) ? expf(lg - m) : 0.f;
    float sum = e;
    sum += __shfl_xor(sum, 1);
    sum += __shfl_xor(sum, 2);
    sum += __shfl_xor(sum, 4);
    sum += __shfl_xor(sum, 8);

    float lse = m + logf(sum);
    if (j < 10 && img < B) out[(size_t)img * 10 + j] = lg - lse;
}

extern "C" void kernel_launch(void* const* d_in, const int* in_sizes, int n_in,
                              void* d_out, int out_size, void* d_ws, size_t ws_size,
                              hipStream_t stream) {
    const float* x    = (const float*)d_in[0];
    const float* wq   = (const float*)d_in[1];
    const float* wfc  = (const float*)d_in[2];
    const float* Wout = (const float*)d_in[3];
    const float* bout = (const float*)d_in[4];
    float* out = (float*)d_out;

    int B = in_sizes[0] / 784;          // 4096
    int blocks = (B + 15) / 16;         // 16 images per 256-thread block
    quanv_hybrid_kernel<<<blocks, 256, 0, stream>>>(x, wq, wfc, Wout, bout, out, B);
}